// Round 5
// baseline (267.325 us; speedup 1.0000x reference)
//
#include <hip/hip_runtime.h>
#include <hip/hip_bf16.h>

// RGCN hetero layer: out[n,f] = sum over relations r, edges (s->n) in r of
//   feat[s,:] @ W[r,:,:]   (D_IN = D_OUT = 64, fp32)
//
// Strategy:
//  - lane f of each wave holds column f of W[r] in 64 VGPRs (loaded once/block)
//  - 4 edges gathered at a time: lanes 0-15 load row of edge0 (float4 each),
//    16-31 edge1, etc. -> one coalesced global_load_dwordx4 per group
//  - rows staged through a per-wave LDS slab, consumed via broadcast
//    ds_read_b128 (16 DS + 64 FMA per edge -> VALU-bound if broadcast is
//    issue-rate; if profile shows DS-bound, switch to 2-edges-per-wave)
//  - software-pipelined: group g+1's idx+row loads are issued before group
//    g's compute (issue-early / consume-late), hiding gather latency
//  - scatter: 64 lanes atomically add the contiguous 256B output row

#define WAVES_PER_BLOCK 4
#define EDGES_PER_WAVE 64               // multiple of 4
#define NGROUPS (EDGES_PER_WAVE / 4)
#define TILE_E (WAVES_PER_BLOCK * EDGES_PER_WAVE)   // 256 edges per block

__global__ __launch_bounds__(256) void rgcn_edge_kernel(
    const float* __restrict__ feat,     // [N, 64]
    const float* __restrict__ weight,   // [R, 64, 64]
    const int*   __restrict__ esrc,     // [R, E]
    const int*   __restrict__ edst,     // [R, E]
    float*       __restrict__ out,      // [N, 64]
    int E, int blocksPerRel)
{
    __shared__ float slab[WAVES_PER_BLOCK][4][64];   // 4 KB: per-wave staging

    const int t    = threadIdx.x;
    const int wave = t >> 6;
    const int lane = t & 63;

    const int r       = blockIdx.x / blocksPerRel;
    const int tileIdx = blockIdx.x % blocksPerRel;
    const int e0      = tileIdx * TILE_E + wave * EDGES_PER_WAVE;

    // --- W column into registers: wreg[d] = weight[r][d][lane] ---
    const float* wbase = weight + (size_t)r * 4096 + lane;
    float wreg[64];
    #pragma unroll
    for (int d = 0; d < 64; ++d) wreg[d] = wbase[(size_t)d * 64];

    const int sub = lane >> 4;   // which of the 4 edges this lane gathers for
    const int q   = lane & 15;   // float4 slot within the 256B row

    const int* srcR = esrc + (size_t)r * E;
    const int* dstR = edst + (size_t)r * E;

    // group loader: gathers 4 src rows (one float4 per lane) + 4 dst indices
    auto load_group = [&](int gbase, float4& a, int dv[4]) {
        const int  e_g  = gbase + sub;
        const int  srow = (e_g < E) ? srcR[e_g] : 0;
        a = ((const float4*)(feat + (size_t)srow * 64))[q];
        if (gbase + 3 < E) {
            const int4 d4 = *(const int4*)(dstR + gbase);
            dv[0] = d4.x; dv[1] = d4.y; dv[2] = d4.z; dv[3] = d4.w;
        } else {
            #pragma unroll
            for (int s = 0; s < 4; ++s)
                dv[s] = (gbase + s < E) ? dstR[gbase + s] : 0;
        }
    };

    if (e0 >= E) return;

    float4 aCur; int dCur[4];
    load_group(e0, aCur, dCur);

    for (int g = 0; g < NGROUPS; ++g) {
        const int ebase = e0 + g * 4;
        if (ebase >= E) break;                    // wave-uniform

        // ---- stage current group's rows into the private slab ----
        *(float4*)&slab[wave][sub][q * 4] = aCur;

        // ---- prefetch next group (loads overlap the compute below) ----
        float4 aNxt = {0.f, 0.f, 0.f, 0.f};
        int dNxt[4] = {0, 0, 0, 0};
        const int enext = ebase + 4;
        const bool hasNext = (g + 1 < NGROUPS) && (enext < E);
        if (hasNext) load_group(enext, aNxt, dNxt);

        // ---- compute + scatter the 4 current edges ----
        #pragma unroll
        for (int s = 0; s < 4; ++s) {
            const int e = ebase + s;
            if (e >= E) break;                    // wave-uniform
            float acc = 0.f;
            #pragma unroll
            for (int d4 = 0; d4 < 16; ++d4) {
                const float4 av = *(const float4*)&slab[wave][s][d4 * 4];
                acc = fmaf(av.x, wreg[4 * d4 + 0], acc);
                acc = fmaf(av.y, wreg[4 * d4 + 1], acc);
                acc = fmaf(av.z, wreg[4 * d4 + 2], acc);
                acc = fmaf(av.w, wreg[4 * d4 + 3], acc);
            }
            atomicAdd(out + (size_t)dCur[s] * 64 + lane, acc);
        }

        aCur = aNxt;
        #pragma unroll
        for (int s = 0; s < 4; ++s) dCur[s] = dNxt[s];
    }
}

extern "C" void kernel_launch(void* const* d_in, const int* in_sizes, int n_in,
                              void* d_out, int out_size, void* d_ws, size_t ws_size,
                              hipStream_t stream) {
    const float* feat   = (const float*)d_in[0];
    const float* weight = (const float*)d_in[1];
    const int*   esrc   = (const int*)d_in[2];
    const int*   edst   = (const int*)d_in[3];
    float*       out    = (float*)d_out;

    const int R = in_sizes[1] / (64 * 64);       // weight is [R,64,64]
    const int E = in_sizes[2] / R;               // edge_src is [R,E]

    // d_out is poisoned with 0xAA before every timed launch -> zero it.
    hipMemsetAsync(d_out, 0, (size_t)out_size * sizeof(float), stream);

    const int blocksPerRel = (E + TILE_E - 1) / TILE_E;
    const dim3 grid(R * blocksPerRel);
    const dim3 block(WAVES_PER_BLOCK * 64);
    rgcn_edge_kernel<<<grid, block, 0, stream>>>(feat, weight, esrc, edst, out,
                                                 E, blocksPerRel);
}

// Round 7
// 263.851 us; speedup vs baseline: 1.0132x; 1.0132x over previous
//
#include <hip/hip_runtime.h>
#include <hip/hip_bf16.h>

// RGCN hetero layer: out[n,f] = sum over relations r, edges (s->n) in r of
//   feat[s,:] @ W[r,:,:]   (D_IN = D_OUT = 64, fp32)
//
// R5 result: 199.6us, WRITE_SIZE==atomic volume (204.8MB) @ 1.03 TB/s.
// Ambiguous between DS-broadcast-bound and atomic-ceiling-bound.
// R6 change: eliminate LDS broadcast entirely. Edge indices arrive via ONE
// coalesced dword load per wave-chunk (lane i holds edge e0+i's src/dst);
// per edge, readlane() gives the src row as an SGPR, so the 16 float4
// feat-row loads are uniform-address (scalarizable to s_load / broadcast L1
// VMEM). W columns stay in 64 VGPRs. Atomic scatter unchanged -> clean A/B.

#define WAVES_PER_BLOCK 4
#define EDGES_PER_WAVE 64
#define TILE_E (WAVES_PER_BLOCK * EDGES_PER_WAVE)   // 256 edges per block

__global__ __launch_bounds__(256) void rgcn_edge_kernel(
    const float* __restrict__ feat,     // [N, 64]
    const float* __restrict__ weight,   // [R, 64, 64]
    const int*   __restrict__ esrc,     // [R, E]
    const int*   __restrict__ edst,     // [R, E]
    float*       __restrict__ out,      // [N, 64]
    int E, int blocksPerRel)
{
    const int t    = threadIdx.x;
    const int wave = t >> 6;
    const int lane = t & 63;

    const int r       = blockIdx.x / blocksPerRel;
    const int tileIdx = blockIdx.x % blocksPerRel;
    const int e0      = tileIdx * TILE_E + wave * EDGES_PER_WAVE;
    if (e0 >= E) return;                       // wave-uniform exit

    // --- W column into registers: wreg[d] = weight[r][d][lane] ---
    const float* wbase = weight + (size_t)r * 4096 + lane;
    float wreg[64];
    #pragma unroll
    for (int d = 0; d < 64; ++d) wreg[d] = wbase[(size_t)d * 64];

    // --- edge indices for this wave-chunk: lane i holds edge e0+i ---
    const int nE = min(EDGES_PER_WAVE, E - e0);
    const int ei = e0 + min(lane, nE - 1);     // clamp tail (values unused)
    const int sv = esrc[(size_t)r * E + ei];
    const int dv = edst[(size_t)r * E + ei];

    float* outl = out + lane;

    for (int i = 0; i < nE; ++i) {
        const int srow = __builtin_amdgcn_readlane(sv, i);   // SGPR-uniform
        const int drow = __builtin_amdgcn_readlane(dv, i);   // SGPR-uniform

        const float4* xp = (const float4*)(feat + (size_t)srow * 64);
        float a0 = 0.f, a1 = 0.f, a2 = 0.f, a3 = 0.f;
        #pragma unroll
        for (int c = 0; c < 16; ++c) {
            const float4 v = xp[c];            // uniform addr: s_load / bcast
            a0 = fmaf(v.x, wreg[4 * c + 0], a0);
            a1 = fmaf(v.y, wreg[4 * c + 1], a1);
            a2 = fmaf(v.z, wreg[4 * c + 2], a2);
            a3 = fmaf(v.w, wreg[4 * c + 3], a3);
        }
        const float acc = (a0 + a1) + (a2 + a3);

        atomicAdd(outl + (size_t)drow * 64, acc);
    }
}

extern "C" void kernel_launch(void* const* d_in, const int* in_sizes, int n_in,
                              void* d_out, int out_size, void* d_ws, size_t ws_size,
                              hipStream_t stream) {
    const float* feat   = (const float*)d_in[0];
    const float* weight = (const float*)d_in[1];
    const int*   esrc   = (const int*)d_in[2];
    const int*   edst   = (const int*)d_in[3];
    float*       out    = (float*)d_out;

    const int R = in_sizes[1] / (64 * 64);       // weight is [R,64,64]
    const int E = in_sizes[2] / R;               // edge_src is [R,E]

    // d_out is poisoned with 0xAA before every timed launch -> zero it.
    hipMemsetAsync(d_out, 0, (size_t)out_size * sizeof(float), stream);

    const int blocksPerRel = (E + TILE_E - 1) / TILE_E;
    const dim3 grid(R * blocksPerRel);
    const dim3 block(WAVES_PER_BLOCK * 64);
    rgcn_edge_kernel<<<grid, block, 0, stream>>>(feat, weight, esrc, edst, out,
                                                 E, blocksPerRel);
}